// Round 7
// baseline (404.781 us; speedup 1.0000x reference)
//
#include <hip/hip_runtime.h>
#include <math.h>

using short8 = __attribute__((ext_vector_type(8))) short;
using f32x4  = __attribute__((ext_vector_type(4))) float;
typedef unsigned short ushort;

__device__ inline ushort f2bf(float f) {
    union { float f; unsigned int i; } v; v.f = f;
    unsigned int x = v.i;
    return (ushort)((x + 0x7FFFu + ((x >> 16) & 1u)) >> 16);
}
__device__ inline void st_out(float* p, float v) { *p = v; }
__device__ inline void st_out(ushort* p, float v) { *p = f2bf(v); }

__device__ inline void gl_lds16(const ushort* g, ushort* l) {
    __builtin_amdgcn_global_load_lds((const __attribute__((address_space(1))) unsigned int*)g,
                                     (__attribute__((address_space(3))) unsigned int*)l, 16, 0, 0);
}
#define MFMA __builtin_amdgcn_mfma_f32_16x16x32_bf16

// ---------------- LayerNorm: one block per row of 1024; fp32 in, bf16 out ----------------
__global__ __launch_bounds__(256) void ln_kernel(const float* __restrict__ x,
                                                 const float* __restrict__ g,
                                                 const float* __restrict__ b,
                                                 ushort* __restrict__ y) {
    int row = blockIdx.x;
    const float* xr = x + (size_t)row * 1024;
    int t = threadIdx.x;
    float v[4];
    float s = 0.f, s2 = 0.f;
#pragma unroll
    for (int i = 0; i < 4; i++) {
        v[i] = xr[t + i * 256];
        s += v[i]; s2 += v[i] * v[i];
    }
#pragma unroll
    for (int off = 1; off < 64; off <<= 1) {
        s += __shfl_xor(s, off); s2 += __shfl_xor(s2, off);
    }
    __shared__ float ps[8];
    int w = t >> 6;
    if ((t & 63) == 0) { ps[w] = s; ps[4 + w] = s2; }
    __syncthreads();
    s  = ps[0] + ps[1] + ps[2] + ps[3];
    s2 = ps[4] + ps[5] + ps[6] + ps[7];
    float mu   = s * (1.0f / 1024.0f);
    float var  = s2 * (1.0f / 1024.0f) - mu * mu;
    float rinv = rsqrtf(var + 1e-5f);
    ushort* yr = y + (size_t)row * 1024;
#pragma unroll
    for (int i = 0; i < 4; i++) {
        int c = t + i * 256;
        yr[c] = f2bf((v[i] - mu) * rinv * g[c] + b[c]);
    }
}

// ------------- weight transpose+convert: fp32 [K,N] -> bf16 [N,K] -------------
__global__ __launch_bounds__(256) void wt_kernel(const float* __restrict__ s,
                                                 ushort* __restrict__ d, int K, int N) {
    __shared__ float tile[32][33];
    int n0 = blockIdx.x * 32, k0 = blockIdx.y * 32;
    int tx = threadIdx.x & 31, ty = threadIdx.x >> 5;
#pragma unroll
    for (int i = 0; i < 4; i++)
        tile[ty + i * 8][tx] = s[(size_t)(k0 + ty + i * 8) * N + n0 + tx];
    __syncthreads();
#pragma unroll
    for (int i = 0; i < 4; i++)
        d[(size_t)(n0 + ty + i * 8) * K + k0 + tx] = f2bf(tile[tx][ty + i * 8]);
}

// -------- bf16 MFMA GEMM: C = A[M,K] @ Bt[N,K]^T, 128x128 tile, BK=64 --------
// EPI: 0 plain, 1 += fp32 R, 2 exact GELU, 3 QKV-split (Q,K -> C stride 2048; V -> VT[d][t])
template <int EPI, typename CT>
__global__ __launch_bounds__(256) void gemm_kernel(const ushort* __restrict__ A,
                                                   const ushort* __restrict__ Bt,
                                                   CT* __restrict__ C,
                                                   const float* __restrict__ R,
                                                   ushort* __restrict__ VT,
                                                   int M, int N, int K) {
    __shared__ alignas(16) ushort As[128 * 64];
    __shared__ alignas(16) ushort Bs[128 * 64];
    int t = threadIdx.x, lane = t & 63, w = t >> 6;
    int bm = blockIdx.y * 128, bn = blockIdx.x * 128;
    int wm = (w >> 1) * 64, wn = (w & 1) * 64;
    f32x4 acc[4][4] = {};
    int srow = lane >> 3;                    // 0..7 row within 8-row group
    int schunk = (lane & 7) ^ (lane >> 3);   // swizzled 8-elem chunk
    int rs = lane & 15, qd = lane >> 4;

    for (int k0 = 0; k0 < K; k0 += 64) {
        __syncthreads();
#pragma unroll
        for (int i = 0; i < 4; i++) {
            int rr = w * 32 + i * 8;
            gl_lds16(A  + (size_t)(bm + rr + srow) * K + k0 + schunk * 8, &As[rr * 64]);
            gl_lds16(Bt + (size_t)(bn + rr + srow) * K + k0 + schunk * 8, &Bs[rr * 64]);
        }
        __syncthreads();
#pragma unroll
        for (int half = 0; half < 2; half++) {
            int cq = qd + half * 4;
            short8 af[4], bf[4];
#pragma unroll
            for (int i = 0; i < 4; i++) {
                int ml = wm + i * 16 + rs;
                af[i] = *(const short8*)&As[ml * 64 + ((cq ^ (ml & 7)) * 8)];
                int nl = wn + i * 16 + rs;
                bf[i] = *(const short8*)&Bs[nl * 64 + ((cq ^ (nl & 7)) * 8)];
            }
#pragma unroll
            for (int mi = 0; mi < 4; mi++)
#pragma unroll
                for (int ni = 0; ni < 4; ni++)
                    acc[mi][ni] = MFMA(af[mi], bf[ni], acc[mi][ni], 0, 0, 0);
        }
    }
#pragma unroll
    for (int mi = 0; mi < 4; mi++)
#pragma unroll
        for (int ni = 0; ni < 4; ni++) {
            int row = bm + wm + mi * 16 + qd * 4;
            int col = bn + wn + ni * 16 + rs;
            if (EPI == 3) {
                if (col < 2048) {
#pragma unroll
                    for (int r = 0; r < 4; r++)
                        ((ushort*)C)[(size_t)(row + r) * 2048 + col] = f2bf(acc[mi][ni][r]);
                } else {
                    int rel = col - 2048, hh = rel >> 6, dd = rel & 63;
                    ushort tmp[4];
#pragma unroll
                    for (int r = 0; r < 4; r++) tmp[r] = f2bf(acc[mi][ni][r]);
                    size_t base = ((size_t)((row >> 11) * 16 + hh) * 64 + dd) * 2048 + (row & 2047);
                    *(uint2*)&VT[base] = *(uint2*)tmp;
                }
            } else {
#pragma unroll
                for (int r = 0; r < 4; r++) {
                    float v = acc[mi][ni][r];
                    size_t idx = (size_t)(row + r) * N + col;
                    if (EPI == 1) v += R[idx];
                    if (EPI == 2) v = 0.5f * v * (1.0f + erff(v * 0.70710678118f));
                    st_out(&C[idx], v);
                }
            }
        }
}

// -------- bf16 MFMA GEMM: 128(M) x 64(N) tile, BK=64, optional split-K (grid.z) --------
template <int EPI, typename CT>
__global__ __launch_bounds__(256) void gemm_n64_kernel(const ushort* __restrict__ A,
                                                       const ushort* __restrict__ Bt,
                                                       CT* __restrict__ C,
                                                       const float* __restrict__ R,
                                                       int M, int N, int K, int Kh) {
    __shared__ alignas(16) ushort As[128 * 64];
    __shared__ alignas(16) ushort Bs[64 * 64];
    int t = threadIdx.x, lane = t & 63, w = t >> 6;
    int bm = blockIdx.x * 128, bn = blockIdx.y * 64;
    int kbeg = blockIdx.z * Kh;
    int wm = (w >> 1) * 64, wn = (w & 1) * 32;
    f32x4 acc[4][2] = {};
    int srow = lane >> 3;
    int schunk = (lane & 7) ^ (lane >> 3);
    int rs = lane & 15, qd = lane >> 4;

    for (int k0 = kbeg; k0 < kbeg + Kh; k0 += 64) {
        __syncthreads();
#pragma unroll
        for (int i = 0; i < 4; i++) {
            int rr = w * 32 + i * 8;
            gl_lds16(A + (size_t)(bm + rr + srow) * K + k0 + schunk * 8, &As[rr * 64]);
        }
#pragma unroll
        for (int i = 0; i < 2; i++) {
            int rr = w * 16 + i * 8;
            gl_lds16(Bt + (size_t)(bn + rr + srow) * K + k0 + schunk * 8, &Bs[rr * 64]);
        }
        __syncthreads();
#pragma unroll
        for (int half = 0; half < 2; half++) {
            int cq = qd + half * 4;
            short8 af[4], bfr[2];
#pragma unroll
            for (int i = 0; i < 4; i++) {
                int ml = wm + i * 16 + rs;
                af[i] = *(const short8*)&As[ml * 64 + ((cq ^ (ml & 7)) * 8)];
            }
#pragma unroll
            for (int j = 0; j < 2; j++) {
                int nl = wn + j * 16 + rs;
                bfr[j] = *(const short8*)&Bs[nl * 64 + ((cq ^ (nl & 7)) * 8)];
            }
#pragma unroll
            for (int mi = 0; mi < 4; mi++)
#pragma unroll
                for (int ni = 0; ni < 2; ni++)
                    acc[mi][ni] = MFMA(af[mi], bfr[ni], acc[mi][ni], 0, 0, 0);
        }
    }
#pragma unroll
    for (int mi = 0; mi < 4; mi++)
#pragma unroll
        for (int ni = 0; ni < 2; ni++) {
            int row = bm + wm + mi * 16 + qd * 4;
            int col = bn + wn + ni * 16 + rs;
#pragma unroll
            for (int r = 0; r < 4; r++) {
                float v = acc[mi][ni][r];
                size_t idx = (size_t)(row + r) * N + col;
                if (EPI == 4) {
                    atomicAdd((float*)&C[idx], v);
                } else {
                    if (EPI == 1) v += R[idx];
                    st_out(&C[idx], v);
                }
            }
        }
}

// -------- causal flash attention, split-K: grid (32 qtile, 32 bh, 4 z), <=4 k-tiles/block --
// Partial o (fp32) atomically accumulated into accO; partial l into accL. No running max.
__global__ __launch_bounds__(256) void attn_kernel(const ushort* __restrict__ qk,
                                                   const ushort* __restrict__ vT,
                                                   float* __restrict__ accO,
                                                   float* __restrict__ accL) {
    int qi = blockIdx.x;
    int nk = qi / 2 + 1;                  // k-tiles of 128 covering [0, q0+64)
    int t0 = blockIdx.z * 4;
    if (t0 >= nk) return;
    int t1 = min(t0 + 4, nk);
    __shared__ alignas(16) ushort Ks[128 * 64];
    __shared__ alignas(16) ushort VTs[64 * 128];
    __shared__ alignas(16) ushort Ps[4 * 16 * 136];
    int t = threadIdx.x, lane = t & 63, w = t >> 6;
    int q0 = qi * 64;
    int bh = blockIdx.y, bb = bh >> 4, h = bh & 15;
    const ushort* qkb = qk + (size_t)bb * 2048 * 2048;
    const ushort* qptr = qkb + h * 64;
    const ushort* kptr = qkb + 1024 + h * 64;
    const ushort* vtb  = vT + (size_t)bh * 64 * 2048;
    int rs = lane & 15, qd = lane >> 4;
    int qrow = q0 + w * 16 + rs;
    short8 aq0 = *(const short8*)(qptr + (size_t)qrow * 2048 + qd * 8);
    short8 aq1 = *(const short8*)(qptr + (size_t)qrow * 2048 + 32 + qd * 8);
    f32x4 o_acc[4] = {};
    float l_part[4] = {0.f, 0.f, 0.f, 0.f};
    int myq = q0 + w * 16 + qd * 4;
    int krl = lane >> 3, kch = lane & 7;
    int vrl = lane >> 4, vch = lane & 15;

    for (int kt = t0; kt < t1; kt++) {
        int k0 = kt * 128;
        __syncthreads();
#pragma unroll
        for (int i = 0; i < 4; i++) {
            int kk = w * 32 + i * 8 + krl;
            gl_lds16(kptr + (size_t)(k0 + kk) * 2048 + ((kch ^ (kk & 7)) * 8), &Ks[(w * 32 + i * 8) * 64]);
            int dd = w * 16 + i * 4 + vrl;
            gl_lds16(vtb + (size_t)dd * 2048 + k0 + ((vch ^ (dd & 15)) * 8), &VTs[(w * 16 + i * 4) * 128]);
        }
        __syncthreads();
        f32x4 s[8];
#pragma unroll
        for (int c = 0; c < 8; c++) {
            int kk = c * 16 + rs;
            short8 kf0 = *(const short8*)&Ks[kk * 64 + ((qd ^ (kk & 7)) * 8)];
            short8 kf1 = *(const short8*)&Ks[kk * 64 + (((qd + 4) ^ (kk & 7)) * 8)];
            f32x4 z = {};
            z = MFMA(aq0, kf0, z, 0, 0, 0);
            z = MFMA(aq1, kf1, z, 0, 0, 0);
            s[c] = z;
        }
        bool lastt = (kt == nk - 1);
#pragma unroll
        for (int c = 0; c < 8; c++) {
            int kk = k0 + c * 16 + rs;
#pragma unroll
            for (int r = 0; r < 4; r++) {
                float p = __expf(s[c][r] * 0.125f);
                if (lastt && (kk > myq + r)) p = 0.f;
                s[c][r] = p;
                l_part[r] += p;
            }
        }
#pragma unroll
        for (int r = 0; r < 4; r++)
#pragma unroll
            for (int c = 0; c < 8; c++)
                Ps[(w * 16 + qd * 4 + r) * 136 + c * 16 + rs] = f2bf(s[c][r]);
        short8 ap[4];
#pragma unroll
        for (int kc = 0; kc < 4; kc++)
            ap[kc] = *(const short8*)&Ps[(w * 16 + rs) * 136 + kc * 32 + qd * 8];
#pragma unroll
        for (int dt = 0; dt < 4; dt++) {
            int dd = dt * 16 + rs;
#pragma unroll
            for (int kc = 0; kc < 4; kc++) {
                int g = kc * 4 + qd;
                short8 bv = *(const short8*)&VTs[dd * 128 + ((g ^ (dd & 15)) * 8)];
                o_acc[dt] = MFMA(ap[kc], bv, o_acc[dt], 0, 0, 0);
            }
        }
    }
#pragma unroll
    for (int r = 0; r < 4; r++)
#pragma unroll
        for (int off = 1; off < 16; off <<= 1)
            l_part[r] += __shfl_xor(l_part[r], off);
#pragma unroll
    for (int dt = 0; dt < 4; dt++)
#pragma unroll
        for (int r = 0; r < 4; r++)
            atomicAdd(&accO[(size_t)(bb * 2048 + myq + r) * 1024 + h * 64 + dt * 16 + rs], o_acc[dt][r]);
    if (rs == 0)
#pragma unroll
        for (int r = 0; r < 4; r++)
            atomicAdd(&accL[(size_t)(bb * 2048 + myq + r) * 16 + h], l_part[r]);
}

// -------- finalize: attnO_bf16[row, c] = accO[row, c] / accL[row, c/64] --------
__global__ __launch_bounds__(256) void attn_fin_kernel(const float* __restrict__ accO,
                                                       const float* __restrict__ accL,
                                                       ushort* __restrict__ outp) {
    int row = blockIdx.x;
    int c0 = threadIdx.x * 4;
    float inv = 1.0f / accL[row * 16 + (c0 >> 6)];
    float4 o = *(const float4*)(accO + (size_t)row * 1024 + c0);
    ushort r4[4] = { f2bf(o.x * inv), f2bf(o.y * inv), f2bf(o.z * inv), f2bf(o.w * inv) };
    *(uint2*)(outp + (size_t)row * 1024 + c0) = *(uint2*)r4;
}

extern "C" void kernel_launch(void* const* d_in, const int* in_sizes, int n_in,
                              void* d_out, int out_size, void* d_ws, size_t ws_size,
                              hipStream_t stream) {
    const float* x     = (const float*)d_in[0];
    const float* ln1g  = (const float*)d_in[1];
    const float* ln1b  = (const float*)d_in[2];
    const float* wqkv  = (const float*)d_in[3];
    const float* wproj = (const float*)d_in[4];
    const float* ln2g  = (const float*)d_in[5];
    const float* ln2b  = (const float*)d_in[6];
    const float* wfc1  = (const float*)d_in[7];
    const float* wfc2  = (const float*)d_in[8];
    float* out = (float*)d_out;
    char* ws = (char*)d_ws;
    const size_t MB = 1024 * 1024;

    // ws: wbufA [0,8M); lnbuf/attnO [8,16M); qk [16,32M); vT [32,40M); accL [40,40.25M)
    // accO = d_out (fp32 scratch, dead until proj). FFN: hmid overlays qk; wbufB after.
    ushort* wbufA = (ushort*)(ws);
    ushort* lnbuf = (ushort*)(ws + 8 * MB);
    ushort* qk    = (ushort*)(ws + 16 * MB);
    ushort* vT    = (ushort*)(ws + 32 * MB);
    float*  accL  = (float*)(ws + 40 * MB);
    float*  accO  = out;
    const int Rr = 4096;

    ln_kernel<<<Rr, 256, 0, stream>>>(x, ln1g, ln1b, lnbuf);
    wt_kernel<<<dim3(3072 / 32, 1024 / 32), 256, 0, stream>>>(wqkv, wbufA, 1024, 3072);
    gemm_kernel<3, ushort><<<dim3(3072 / 128, Rr / 128), 256, 0, stream>>>(lnbuf, wbufA, qk, nullptr, vT, Rr, 3072, 1024);
    hipMemsetAsync(accO, 0, (size_t)Rr * 1024 * 4, stream);
    hipMemsetAsync(accL, 0, (size_t)Rr * 16 * 4, stream);
    attn_kernel<<<dim3(32, 32, 4), 256, 0, stream>>>(qk, vT, accO, accL);
    attn_fin_kernel<<<Rr, 256, 0, stream>>>(accO, accL, lnbuf);  // attnO -> lnbuf
    wt_kernel<<<dim3(1024 / 32, 1024 / 32), 256, 0, stream>>>(wproj, wbufA, 1024, 1024);
    gemm_n64_kernel<1, float><<<dim3(Rr / 128, 1024 / 64, 1), 256, 0, stream>>>(lnbuf, wbufA, out, x, Rr, 1024, 1024, 1024);
    ln_kernel<<<Rr, 256, 0, stream>>>(out, ln2g, ln2b, lnbuf);
    wt_kernel<<<dim3(4096 / 32, 1024 / 32), 256, 0, stream>>>(wfc1, wbufA, 1024, 4096);

    if (ws_size >= 56 * MB) {
        ushort* hmid  = qk;                                  // [16,48M)
        ushort* wbufB = (ushort*)(ws + 48 * MB);
        wt_kernel<<<dim3(1024 / 32, 4096 / 32), 256, 0, stream>>>(wfc2, wbufB, 4096, 1024);
        gemm_kernel<2, ushort><<<dim3(4096 / 128, Rr / 128), 256, 0, stream>>>(lnbuf, wbufA, hmid, nullptr, nullptr, Rr, 4096, 1024);
        gemm_n64_kernel<4, float><<<dim3(Rr / 128, 1024 / 64, 2), 256, 0, stream>>>(hmid, wbufB, out, nullptr, Rr, 1024, 4096, 2048);
    } else {
        ushort* hmid  = qk;                                  // [16,32M)
        ushort* wbufB = (ushort*)(ws + 32 * MB);             // vT dead in FFN phase
        wt_kernel<<<dim3(1024 / 32, 4096 / 32), 256, 0, stream>>>(wfc2, wbufB, 4096, 1024);
        for (int hf = 0; hf < 2; hf++) {
            const ushort* lnh = lnbuf + (size_t)hf * 2048 * 1024;
            float* outh = out + (size_t)hf * 2048 * 1024;
            gemm_kernel<2, ushort><<<dim3(4096 / 128, 2048 / 128), 256, 0, stream>>>(lnh, wbufA, hmid, nullptr, nullptr, 2048, 4096, 1024);
            gemm_n64_kernel<4, float><<<dim3(2048 / 128, 1024 / 64, 2), 256, 0, stream>>>(hmid, wbufB, outh, nullptr, 2048, 1024, 4096, 2048);
        }
    }
}

// Round 8
// 368.928 us; speedup vs baseline: 1.0972x; 1.0972x over previous
//
#include <hip/hip_runtime.h>
#include <math.h>

using short8 = __attribute__((ext_vector_type(8))) short;
using f32x4  = __attribute__((ext_vector_type(4))) float;
typedef unsigned short ushort;

__device__ inline ushort f2bf(float f) {
    union { float f; unsigned int i; } v; v.f = f;
    unsigned int x = v.i;
    return (ushort)((x + 0x7FFFu + ((x >> 16) & 1u)) >> 16);
}
__device__ inline ushort f2bf_hu(float f) {  // round-half-up (cheap, ~unbiased for p>=0)
    union { float f; unsigned int i; } v; v.f = f;
    return (ushort)((v.i + 0x8000u) >> 16);
}
__device__ inline void st_out(float* p, float v) { *p = v; }
__device__ inline void st_out(ushort* p, float v) { *p = f2bf(v); }

__device__ inline void gl_lds16(const ushort* g, ushort* l) {
    __builtin_amdgcn_global_load_lds((const __attribute__((address_space(1))) unsigned int*)g,
                                     (__attribute__((address_space(3))) unsigned int*)l, 16, 0, 0);
}
#define MFMA __builtin_amdgcn_mfma_f32_16x16x32_bf16

// ---------------- LayerNorm: one block per row of 1024; fp32 in, bf16 out ----------------
__global__ __launch_bounds__(256) void ln_kernel(const float* __restrict__ x,
                                                 const float* __restrict__ g,
                                                 const float* __restrict__ b,
                                                 ushort* __restrict__ y) {
    int row = blockIdx.x;
    const float* xr = x + (size_t)row * 1024;
    int t = threadIdx.x;
    float v[4];
    float s = 0.f, s2 = 0.f;
#pragma unroll
    for (int i = 0; i < 4; i++) {
        v[i] = xr[t + i * 256];
        s += v[i]; s2 += v[i] * v[i];
    }
#pragma unroll
    for (int off = 1; off < 64; off <<= 1) {
        s += __shfl_xor(s, off); s2 += __shfl_xor(s2, off);
    }
    __shared__ float ps[8];
    int w = t >> 6;
    if ((t & 63) == 0) { ps[w] = s; ps[4 + w] = s2; }
    __syncthreads();
    s  = ps[0] + ps[1] + ps[2] + ps[3];
    s2 = ps[4] + ps[5] + ps[6] + ps[7];
    float mu   = s * (1.0f / 1024.0f);
    float var  = s2 * (1.0f / 1024.0f) - mu * mu;
    float rinv = rsqrtf(var + 1e-5f);
    ushort* yr = y + (size_t)row * 1024;
#pragma unroll
    for (int i = 0; i < 4; i++) {
        int c = t + i * 256;
        yr[c] = f2bf((v[i] - mu) * rinv * g[c] + b[c]);
    }
}

// ------------- weight transpose+convert: fp32 [K,N] -> bf16 [N,K] -------------
__global__ __launch_bounds__(256) void wt_kernel(const float* __restrict__ s,
                                                 ushort* __restrict__ d, int K, int N) {
    __shared__ float tile[32][33];
    int n0 = blockIdx.x * 32, k0 = blockIdx.y * 32;
    int tx = threadIdx.x & 31, ty = threadIdx.x >> 5;
#pragma unroll
    for (int i = 0; i < 4; i++)
        tile[ty + i * 8][tx] = s[(size_t)(k0 + ty + i * 8) * N + n0 + tx];
    __syncthreads();
#pragma unroll
    for (int i = 0; i < 4; i++)
        d[(size_t)(n0 + ty + i * 8) * K + k0 + tx] = f2bf(tile[tx][ty + i * 8]);
}

// -------- bf16 MFMA GEMM: C = A[M,K] @ Bt[N,K]^T, 128x128 tile, BK=64 --------
// EPI: 0 plain, 1 += fp32 R, 2 exact GELU, 3 QKV-split (Q*0.125,K -> qk; V -> VT[d][t])
template <int EPI, typename CT>
__global__ __launch_bounds__(256) void gemm_kernel(const ushort* __restrict__ A,
                                                   const ushort* __restrict__ Bt,
                                                   CT* __restrict__ C,
                                                   const float* __restrict__ R,
                                                   ushort* __restrict__ VT,
                                                   int M, int N, int K) {
    __shared__ alignas(16) ushort As[128 * 64];
    __shared__ alignas(16) ushort Bs[128 * 64];
    int t = threadIdx.x, lane = t & 63, w = t >> 6;
    int bm = blockIdx.y * 128, bn = blockIdx.x * 128;
    int wm = (w >> 1) * 64, wn = (w & 1) * 64;
    f32x4 acc[4][4] = {};
    int srow = lane >> 3;
    int schunk = (lane & 7) ^ (lane >> 3);
    int rs = lane & 15, qd = lane >> 4;

    for (int k0 = 0; k0 < K; k0 += 64) {
        __syncthreads();
#pragma unroll
        for (int i = 0; i < 4; i++) {
            int rr = w * 32 + i * 8;
            gl_lds16(A  + (size_t)(bm + rr + srow) * K + k0 + schunk * 8, &As[rr * 64]);
            gl_lds16(Bt + (size_t)(bn + rr + srow) * K + k0 + schunk * 8, &Bs[rr * 64]);
        }
        __syncthreads();
#pragma unroll
        for (int half = 0; half < 2; half++) {
            int cq = qd + half * 4;
            short8 af[4], bf[4];
#pragma unroll
            for (int i = 0; i < 4; i++) {
                int ml = wm + i * 16 + rs;
                af[i] = *(const short8*)&As[ml * 64 + ((cq ^ (ml & 7)) * 8)];
                int nl = wn + i * 16 + rs;
                bf[i] = *(const short8*)&Bs[nl * 64 + ((cq ^ (nl & 7)) * 8)];
            }
#pragma unroll
            for (int mi = 0; mi < 4; mi++)
#pragma unroll
                for (int ni = 0; ni < 4; ni++)
                    acc[mi][ni] = MFMA(af[mi], bf[ni], acc[mi][ni], 0, 0, 0);
        }
    }
#pragma unroll
    for (int mi = 0; mi < 4; mi++)
#pragma unroll
        for (int ni = 0; ni < 4; ni++) {
            int row = bm + wm + mi * 16 + qd * 4;
            int col = bn + wn + ni * 16 + rs;
            if (EPI == 3) {
                if (col < 2048) {
                    float sc = (col < 1024) ? 0.125f : 1.0f;  // pre-scale Q by 1/sqrt(d)
#pragma unroll
                    for (int r = 0; r < 4; r++)
                        ((ushort*)C)[(size_t)(row + r) * 2048 + col] = f2bf(acc[mi][ni][r] * sc);
                } else {
                    int rel = col - 2048, hh = rel >> 6, dd = rel & 63;
                    ushort tmp[4];
#pragma unroll
                    for (int r = 0; r < 4; r++) tmp[r] = f2bf(acc[mi][ni][r]);
                    size_t base = ((size_t)((row >> 11) * 16 + hh) * 64 + dd) * 2048 + (row & 2047);
                    *(uint2*)&VT[base] = *(uint2*)tmp;
                }
            } else {
#pragma unroll
                for (int r = 0; r < 4; r++) {
                    float v = acc[mi][ni][r];
                    size_t idx = (size_t)(row + r) * N + col;
                    if (EPI == 1) v += R[idx];
                    if (EPI == 2) v = 0.5f * v * (1.0f + erff(v * 0.70710678118f));
                    st_out(&C[idx], v);
                }
            }
        }
}

// -------- bf16 MFMA GEMM: 128(M) x 64(N) tile, BK=64, optional split-K (grid.z) --------
template <int EPI, typename CT>
__global__ __launch_bounds__(256) void gemm_n64_kernel(const ushort* __restrict__ A,
                                                       const ushort* __restrict__ Bt,
                                                       CT* __restrict__ C,
                                                       const float* __restrict__ R,
                                                       int M, int N, int K, int Kh) {
    __shared__ alignas(16) ushort As[128 * 64];
    __shared__ alignas(16) ushort Bs[64 * 64];
    int t = threadIdx.x, lane = t & 63, w = t >> 6;
    int bm = blockIdx.x * 128, bn = blockIdx.y * 64;
    int kbeg = blockIdx.z * Kh;
    int wm = (w >> 1) * 64, wn = (w & 1) * 32;
    f32x4 acc[4][2] = {};
    int srow = lane >> 3;
    int schunk = (lane & 7) ^ (lane >> 3);
    int rs = lane & 15, qd = lane >> 4;

    for (int k0 = kbeg; k0 < kbeg + Kh; k0 += 64) {
        __syncthreads();
#pragma unroll
        for (int i = 0; i < 4; i++) {
            int rr = w * 32 + i * 8;
            gl_lds16(A + (size_t)(bm + rr + srow) * K + k0 + schunk * 8, &As[rr * 64]);
        }
#pragma unroll
        for (int i = 0; i < 2; i++) {
            int rr = w * 16 + i * 8;
            gl_lds16(Bt + (size_t)(bn + rr + srow) * K + k0 + schunk * 8, &Bs[rr * 64]);
        }
        __syncthreads();
#pragma unroll
        for (int half = 0; half < 2; half++) {
            int cq = qd + half * 4;
            short8 af[4], bfr[2];
#pragma unroll
            for (int i = 0; i < 4; i++) {
                int ml = wm + i * 16 + rs;
                af[i] = *(const short8*)&As[ml * 64 + ((cq ^ (ml & 7)) * 8)];
            }
#pragma unroll
            for (int j = 0; j < 2; j++) {
                int nl = wn + j * 16 + rs;
                bfr[j] = *(const short8*)&Bs[nl * 64 + ((cq ^ (nl & 7)) * 8)];
            }
#pragma unroll
            for (int mi = 0; mi < 4; mi++)
#pragma unroll
                for (int ni = 0; ni < 2; ni++)
                    acc[mi][ni] = MFMA(af[mi], bfr[ni], acc[mi][ni], 0, 0, 0);
        }
    }
#pragma unroll
    for (int mi = 0; mi < 4; mi++)
#pragma unroll
        for (int ni = 0; ni < 2; ni++) {
            int row = bm + wm + mi * 16 + qd * 4;
            int col = bn + wn + ni * 16 + rs;
#pragma unroll
            for (int r = 0; r < 4; r++) {
                float v = acc[mi][ni][r];
                size_t idx = (size_t)(row + r) * N + col;
                if (EPI == 4) {
                    atomicAdd((float*)&C[idx], v);
                } else {
                    if (EPI == 1) v += R[idx];
                    st_out(&C[idx], v);
                }
            }
        }
}

// -------- causal flash attention: triangle-paired, split-2, deterministic combine --------
// grid (16 pairs, 32 bh, 2 z). Block covers q-tiles p and 31-p (17 k-tile-units total,
// split 9/8 across z). Tile p fully owned by z=0 -> finalized in-kernel to attnO.
// Tile 31-p: both z write fp32 partials (pO = d_out scratch, pL) with plain stores.
// LDS 32 KB: P (per-wave 4 KB, swizzled) overlays the Ks region after a barrier.
__global__ __launch_bounds__(256) void attn_kernel(const ushort* __restrict__ qk,
                                                   const ushort* __restrict__ vT,
                                                   ushort* __restrict__ attnO,
                                                   float* __restrict__ pO,
                                                   float* __restrict__ pL) {
    __shared__ alignas(16) ushort Ks[128 * 64];   // K tile; wave w's P overlays [w*2048,+2048)
    __shared__ alignas(16) ushort VTs[64 * 128];
    int t = threadIdx.x, lane = t & 63, w = t >> 6;
    int p = blockIdx.x, bh = blockIdx.y, z = blockIdx.z;
    int bb = bh >> 4, h = bh & 15;
    const ushort* qkb = qk + (size_t)bb * 2048 * 2048;
    const ushort* qptr = qkb + h * 64;
    const ushort* kptr = qkb + 1024 + h * 64;
    const ushort* vtb  = vT + (size_t)bh * 64 * 2048;
    int rs = lane & 15, qd = lane >> 4;
    int krl = lane >> 3, kch = lane & 7;
    int vrl = lane >> 4, vch = lane & 15;
    int nkA = p / 2 + 1, nkB = (31 - p) / 2 + 1;
    int qts[2] = {p, 31 - p};
    int nks[2] = {nkA, nkB};
    int kb[2], ke[2];
    if (z == 0) { kb[0] = 0; ke[0] = nkA; kb[1] = 0;       ke[1] = 9 - nkA; }
    else        { kb[0] = 0; ke[0] = 0;   kb[1] = 9 - nkA; ke[1] = nkB;     }
    ushort* Pw = &Ks[w * 2048];   // this wave's P slice [16 rows][128 cols], swizzled

    for (int ph = 0; ph < 2; ph++) {
        if (kb[ph] >= ke[ph]) continue;
        int qt = qts[ph], nk = nks[ph];
        int q0 = qt * 64;
        int qrow = q0 + w * 16 + rs;
        short8 aq0 = *(const short8*)(qptr + (size_t)qrow * 2048 + qd * 8);
        short8 aq1 = *(const short8*)(qptr + (size_t)qrow * 2048 + 32 + qd * 8);
        int myq = q0 + w * 16 + qd * 4;
        f32x4 o_acc[4] = {};
        float l_part[4] = {0.f, 0.f, 0.f, 0.f};

        for (int kt = kb[ph]; kt < ke[ph]; kt++) {
            int k0 = kt * 128;
            __syncthreads();   // prior iter's P/VT reads done before restaging
#pragma unroll
            for (int i = 0; i < 4; i++) {
                int kk = w * 32 + i * 8 + krl;
                gl_lds16(kptr + (size_t)(k0 + kk) * 2048 + ((kch ^ (kk & 7)) * 8), &Ks[(w * 32 + i * 8) * 64]);
                int dd = w * 16 + i * 4 + vrl;
                gl_lds16(vtb + (size_t)dd * 2048 + k0 + ((vch ^ (dd & 15)) * 8), &VTs[(w * 16 + i * 4) * 128]);
            }
            __syncthreads();
            f32x4 s[8];
#pragma unroll
            for (int c = 0; c < 8; c++) {
                int kk = c * 16 + rs;
                short8 kf0 = *(const short8*)&Ks[kk * 64 + ((qd ^ (kk & 7)) * 8)];
                short8 kf1 = *(const short8*)&Ks[kk * 64 + (((qd + 4) ^ (kk & 7)) * 8)];
                f32x4 zz = {};
                zz = MFMA(aq0, kf0, zz, 0, 0, 0);
                zz = MFMA(aq1, kf1, zz, 0, 0, 0);
                s[c] = zz;
            }
            bool lastt = (kt == nk - 1);
#pragma unroll
            for (int c = 0; c < 8; c++) {
                int kk = k0 + c * 16 + rs;
#pragma unroll
                for (int r = 0; r < 4; r++) {
                    float pv = __expf(s[c][r]);   // Q pre-scaled by 1/8
                    if (lastt && (kk > myq + r)) pv = 0.f;
                    s[c][r] = pv;
                    l_part[r] += pv;
                }
            }
            __syncthreads();   // all waves' K-frag reads done before P overlays Ks
#pragma unroll
            for (int r = 0; r < 4; r++) {
                int row = qd * 4 + r;
#pragma unroll
                for (int c = 0; c < 8; c++) {
                    int chunk = c * 2 + (rs >> 3);
                    Pw[row * 128 + ((chunk ^ row) * 8) + (rs & 7)] = f2bf_hu(s[c][r]);
                }
            }
            short8 ap[4];
#pragma unroll
            for (int kc = 0; kc < 4; kc++)
                ap[kc] = *(const short8*)&Pw[rs * 128 + (((kc * 4 + qd) ^ rs) * 8)];
#pragma unroll
            for (int dt = 0; dt < 4; dt++) {
                int dd = dt * 16 + rs;
#pragma unroll
                for (int kc = 0; kc < 4; kc++) {
                    int g = kc * 4 + qd;
                    short8 bv = *(const short8*)&VTs[dd * 128 + ((g ^ (dd & 15)) * 8)];
                    o_acc[dt] = MFMA(ap[kc], bv, o_acc[dt], 0, 0, 0);
                }
            }
        }
#pragma unroll
        for (int r = 0; r < 4; r++)
#pragma unroll
            for (int off = 1; off < 16; off <<= 1)
                l_part[r] += __shfl_xor(l_part[r], off);
        if (ph == 0) {
            // complete tile: finalize directly
#pragma unroll
            for (int dt = 0; dt < 4; dt++)
#pragma unroll
                for (int r = 0; r < 4; r++)
                    attnO[(size_t)(bb * 2048 + myq + r) * 1024 + h * 64 + dt * 16 + rs] =
                        f2bf(o_acc[dt][r] / l_part[r]);
        } else {
            // partial: plain stores, combined later
            int qb16 = 15 - p;
            size_t ob = ((size_t)(z * 32 + bh) * 16 + qb16) * 4096;
#pragma unroll
            for (int dt = 0; dt < 4; dt++)
#pragma unroll
                for (int r = 0; r < 4; r++)
                    pO[ob + (size_t)(w * 16 + qd * 4 + r) * 64 + dt * 16 + rs] = o_acc[dt][r];
            if (rs == 0)
#pragma unroll
                for (int r = 0; r < 4; r++)
                    pL[((size_t)(z * 32 + bh) * 16 + qb16) * 64 + w * 16 + qd * 4 + r] = l_part[r];
        }
    }
}

// -------- combine the two z-partials for q-tiles 16..31 --------
__global__ __launch_bounds__(256) void attn_comb_kernel(const float* __restrict__ pO,
                                                        const float* __restrict__ pL,
                                                        ushort* __restrict__ attnO) {
    int idx4 = (blockIdx.x * 256 + threadIdx.x) * 4;
    int dim = idx4 & 63, row = (idx4 >> 6) & 63, qb = (idx4 >> 12) & 15, bh = idx4 >> 16;
    float4 o0 = *(const float4*)(pO + idx4);
    float4 o1 = *(const float4*)(pO + 2097152 + idx4);
    float inv = 1.0f / (pL[idx4 >> 6] + pL[32768 + (idx4 >> 6)]);
    int grow = (bh >> 4) * 2048 + (16 + qb) * 64 + row;
    int col = (bh & 15) * 64 + dim;
    ushort r4[4] = { f2bf((o0.x + o1.x) * inv), f2bf((o0.y + o1.y) * inv),
                     f2bf((o0.z + o1.z) * inv), f2bf((o0.w + o1.w) * inv) };
    *(uint2*)(attnO + (size_t)grow * 1024 + col) = *(uint2*)r4;
}

extern "C" void kernel_launch(void* const* d_in, const int* in_sizes, int n_in,
                              void* d_out, int out_size, void* d_ws, size_t ws_size,
                              hipStream_t stream) {
    const float* x     = (const float*)d_in[0];
    const float* ln1g  = (const float*)d_in[1];
    const float* ln1b  = (const float*)d_in[2];
    const float* wqkv  = (const float*)d_in[3];
    const float* wproj = (const float*)d_in[4];
    const float* ln2g  = (const float*)d_in[5];
    const float* ln2b  = (const float*)d_in[6];
    const float* wfc1  = (const float*)d_in[7];
    const float* wfc2  = (const float*)d_in[8];
    float* out = (float*)d_out;
    char* ws = (char*)d_ws;
    const size_t MB = 1024 * 1024;

    // ws: wbufA [0,8M); lnbuf/attnO [8,16M); qk [16,32M); vT [32,40M); pL [40,40.25M)
    // pO = d_out (16 MB fp32 scratch, fully overwritten; dead before proj).
    ushort* wbufA = (ushort*)(ws);
    ushort* lnbuf = (ushort*)(ws + 8 * MB);
    ushort* qk    = (ushort*)(ws + 16 * MB);
    ushort* vT    = (ushort*)(ws + 32 * MB);
    float*  pL    = (float*)(ws + 40 * MB);
    const int Rr = 4096;

    ln_kernel<<<Rr, 256, 0, stream>>>(x, ln1g, ln1b, lnbuf);
    wt_kernel<<<dim3(3072 / 32, 1024 / 32), 256, 0, stream>>>(wqkv, wbufA, 1024, 3072);
    gemm_kernel<3, ushort><<<dim3(3072 / 128, Rr / 128), 256, 0, stream>>>(lnbuf, wbufA, qk, nullptr, vT, Rr, 3072, 1024);
    attn_kernel<<<dim3(16, 32, 2), 256, 0, stream>>>(qk, vT, lnbuf, out, pL);
    attn_comb_kernel<<<2048, 256, 0, stream>>>(out, pL, lnbuf);
    wt_kernel<<<dim3(1024 / 32, 1024 / 32), 256, 0, stream>>>(wproj, wbufA, 1024, 1024);
    gemm_n64_kernel<1, float><<<dim3(Rr / 128, 1024 / 64, 1), 256, 0, stream>>>(lnbuf, wbufA, out, x, Rr, 1024, 1024, 1024);
    ln_kernel<<<Rr, 256, 0, stream>>>(out, ln2g, ln2b, lnbuf);
    wt_kernel<<<dim3(4096 / 32, 1024 / 32), 256, 0, stream>>>(wfc1, wbufA, 1024, 4096);

    if (ws_size >= 56 * MB) {
        ushort* hmid  = qk;                                  // [16,48M)
        ushort* wbufB = (ushort*)(ws + 48 * MB);
        wt_kernel<<<dim3(1024 / 32, 4096 / 32), 256, 0, stream>>>(wfc2, wbufB, 4096, 1024);
        gemm_kernel<2, ushort><<<dim3(4096 / 128, Rr / 128), 256, 0, stream>>>(lnbuf, wbufA, hmid, nullptr, nullptr, Rr, 4096, 1024);
        gemm_n64_kernel<4, float><<<dim3(Rr / 128, 1024 / 64, 2), 256, 0, stream>>>(hmid, wbufB, out, nullptr, Rr, 1024, 4096, 2048);
    } else {
        ushort* hmid  = qk;                                  // [16,32M)
        ushort* wbufB = (ushort*)(ws + 32 * MB);             // vT dead in FFN phase
        wt_kernel<<<dim3(1024 / 32, 4096 / 32), 256, 0, stream>>>(wfc2, wbufB, 4096, 1024);
        for (int hf = 0; hf < 2; hf++) {
            const ushort* lnh = lnbuf + (size_t)hf * 2048 * 1024;
            float* outh = out + (size_t)hf * 2048 * 1024;
            gemm_kernel<2, ushort><<<dim3(4096 / 128, 2048 / 128), 256, 0, stream>>>(lnh, wbufA, hmid, nullptr, nullptr, 2048, 4096, 1024);
            gemm_n64_kernel<4, float><<<dim3(2048 / 128, 1024 / 64, 2), 256, 0, stream>>>(hmid, wbufB, outh, nullptr, 2048, 1024, 4096, 2048);
        }
    }
}

// Round 9
// 359.668 us; speedup vs baseline: 1.1254x; 1.0257x over previous
//
#include <hip/hip_runtime.h>
#include <math.h>

using short8 = __attribute__((ext_vector_type(8))) short;
using f32x4  = __attribute__((ext_vector_type(4))) float;
typedef unsigned short ushort;

__device__ inline ushort f2bf(float f) {
    union { float f; unsigned int i; } v; v.f = f;
    unsigned int x = v.i;
    return (ushort)((x + 0x7FFFu + ((x >> 16) & 1u)) >> 16);
}
__device__ inline ushort f2bf_hu(float f) {  // round-half-up (cheap, ~unbiased for p>=0)
    union { float f; unsigned int i; } v; v.f = f;
    return (ushort)((v.i + 0x8000u) >> 16);
}
__device__ inline void st_out(float* p, float v) { *p = v; }
__device__ inline void st_out(ushort* p, float v) { *p = f2bf(v); }

__device__ inline void gl_lds16(const ushort* g, ushort* l) {
    __builtin_amdgcn_global_load_lds((const __attribute__((address_space(1))) unsigned int*)g,
                                     (__attribute__((address_space(3))) unsigned int*)l, 16, 0, 0);
}
#define MFMA __builtin_amdgcn_mfma_f32_16x16x32_bf16

// tanh-approx GELU: ~8 VALU ops, |err| ~1e-3 (bf16 output rounding dominates)
__device__ inline float gelu_fast(float x) {
    float t2 = x * x;
    float y  = x * fmaf(t2, 0.07135481f, 1.5957691f);   // 2c(x + 0.044715 x^3)
    float e  = __expf(y);
    return x * e * __builtin_amdgcn_rcpf(e + 1.0f);
}

// ---------------- LayerNorm: one block per row of 1024; fp32 in, bf16 out ----------------
__global__ __launch_bounds__(256) void ln_kernel(const float* __restrict__ x,
                                                 const float* __restrict__ g,
                                                 const float* __restrict__ b,
                                                 ushort* __restrict__ y) {
    int row = blockIdx.x;
    const float* xr = x + (size_t)row * 1024;
    int t = threadIdx.x;
    float v[4];
    float s = 0.f, s2 = 0.f;
#pragma unroll
    for (int i = 0; i < 4; i++) {
        v[i] = xr[t + i * 256];
        s += v[i]; s2 += v[i] * v[i];
    }
#pragma unroll
    for (int off = 1; off < 64; off <<= 1) {
        s += __shfl_xor(s, off); s2 += __shfl_xor(s2, off);
    }
    __shared__ float ps[8];
    int w = t >> 6;
    if ((t & 63) == 0) { ps[w] = s; ps[4 + w] = s2; }
    __syncthreads();
    s  = ps[0] + ps[1] + ps[2] + ps[3];
    s2 = ps[4] + ps[5] + ps[6] + ps[7];
    float mu   = s * (1.0f / 1024.0f);
    float var  = s2 * (1.0f / 1024.0f) - mu * mu;
    float rinv = rsqrtf(var + 1e-5f);
    ushort* yr = y + (size_t)row * 1024;
#pragma unroll
    for (int i = 0; i < 4; i++) {
        int c = t + i * 256;
        yr[c] = f2bf((v[i] - mu) * rinv * g[c] + b[c]);
    }
}

// ------------- weight transpose+convert: fp32 [K,N] -> bf16 [N,K] -------------
__global__ __launch_bounds__(256) void wt_kernel(const float* __restrict__ s,
                                                 ushort* __restrict__ d, int K, int N) {
    __shared__ float tile[32][33];
    int n0 = blockIdx.x * 32, k0 = blockIdx.y * 32;
    int tx = threadIdx.x & 31, ty = threadIdx.x >> 5;
#pragma unroll
    for (int i = 0; i < 4; i++)
        tile[ty + i * 8][tx] = s[(size_t)(k0 + ty + i * 8) * N + n0 + tx];
    __syncthreads();
#pragma unroll
    for (int i = 0; i < 4; i++)
        d[(size_t)(n0 + ty + i * 8) * K + k0 + tx] = f2bf(tile[tx][ty + i * 8]);
}

// -------- bf16 MFMA GEMM: C = A[M,K] @ Bt[N,K]^T, 128x128 tile, BK=64, bf16 out --------
// EPI: 0 plain, 2 fast GELU, 3 QKV-split (Q*0.125,K -> qk stride 2048; V -> VT[d][t]).
// Epilogue stages C tile through 32 KB SMEM (XOR-swizzled) for 16B coalesced stores.
template <int EPI>
__global__ __launch_bounds__(256) void gemm_kernel(const ushort* __restrict__ A,
                                                   const ushort* __restrict__ Bt,
                                                   ushort* __restrict__ C,
                                                   ushort* __restrict__ VT,
                                                   int M, int N, int K) {
    __shared__ alignas(16) ushort SMEM[128 * 128];   // K-loop: As=[0,8192), Bs=[8192,16384)
    ushort* As = SMEM;
    ushort* Bs = SMEM + 128 * 64;
    int t = threadIdx.x, lane = t & 63, w = t >> 6;
    int bm = blockIdx.y * 128, bn = blockIdx.x * 128;
    int wm = (w >> 1) * 64, wn = (w & 1) * 64;
    f32x4 acc[4][4] = {};
    int srow = lane >> 3;
    int schunk = (lane & 7) ^ (lane >> 3);
    int rs = lane & 15, qd = lane >> 4;

    for (int k0 = 0; k0 < K; k0 += 64) {
        __syncthreads();
#pragma unroll
        for (int i = 0; i < 4; i++) {
            int rr = w * 32 + i * 8;
            gl_lds16(A  + (size_t)(bm + rr + srow) * K + k0 + schunk * 8, &As[rr * 64]);
            gl_lds16(Bt + (size_t)(bn + rr + srow) * K + k0 + schunk * 8, &Bs[rr * 64]);
        }
        __syncthreads();
#pragma unroll
        for (int half = 0; half < 2; half++) {
            int cq = qd + half * 4;
            short8 af[4], bf[4];
#pragma unroll
            for (int i = 0; i < 4; i++) {
                int ml = wm + i * 16 + rs;
                af[i] = *(const short8*)&As[ml * 64 + ((cq ^ (ml & 7)) * 8)];
                int nl = wn + i * 16 + rs;
                bf[i] = *(const short8*)&Bs[nl * 64 + ((cq ^ (nl & 7)) * 8)];
            }
#pragma unroll
            for (int mi = 0; mi < 4; mi++)
#pragma unroll
                for (int ni = 0; ni < 4; ni++)
                    acc[mi][ni] = MFMA(af[mi], bf[ni], acc[mi][ni], 0, 0, 0);
        }
    }

    if (EPI == 3 && bn >= 2048) {
        // V region: direct transposed store (already vectorized)
#pragma unroll
        for (int mi = 0; mi < 4; mi++)
#pragma unroll
            for (int ni = 0; ni < 4; ni++) {
                int row = bm + wm + mi * 16 + qd * 4;
                int col = bn + wn + ni * 16 + rs;
                int rel = col - 2048, hh = rel >> 6, dd = rel & 63;
                ushort tmp[4];
#pragma unroll
                for (int r = 0; r < 4; r++) tmp[r] = f2bf(acc[mi][ni][r]);
                size_t base = ((size_t)((row >> 11) * 16 + hh) * 64 + dd) * 2048 + (row & 2047);
                *(uint2*)&VT[base] = *(uint2*)tmp;
            }
        return;
    }

    // ---- staged epilogue: SMEM[row][chunk^row-swizzle] then 16B coalesced stores ----
    float sc = (EPI == 3 && bn < 1024) ? 0.125f : 1.0f;
    __syncthreads();   // all waves done reading As/Bs
#pragma unroll
    for (int mi = 0; mi < 4; mi++)
#pragma unroll
        for (int ni = 0; ni < 4; ni++) {
            int lcolc = (wn + ni * 16 + rs) >> 3;
            int lcolo = rs & 7;
#pragma unroll
            for (int r = 0; r < 4; r++) {
                int row = wm + mi * 16 + qd * 4 + r;
                float v = acc[mi][ni][r];
                if (EPI == 2) v = gelu_fast(v);
                if (EPI == 3) v *= sc;
                SMEM[row * 128 + ((lcolc ^ (row & 15)) * 8) + lcolo] = f2bf(v);
            }
        }
    __syncthreads();
    int ldC = (EPI == 3) ? 2048 : N;
#pragma unroll
    for (int ps = 0; ps < 8; ps++) {
        int row = ps * 16 + (t >> 4);
        int c = t & 15;
        short8 vv = *(const short8*)&SMEM[row * 128 + ((c ^ (row & 15)) * 8)];
        *(short8*)(C + (size_t)(bm + row) * ldC + bn + c * 8) = vv;
    }
}

// -------- bf16 MFMA GEMM: 128(M) x 64(N) tile, BK=64, optional split-K (grid.z) --------
template <int EPI, typename CT>
__global__ __launch_bounds__(256) void gemm_n64_kernel(const ushort* __restrict__ A,
                                                       const ushort* __restrict__ Bt,
                                                       CT* __restrict__ C,
                                                       const float* __restrict__ R,
                                                       int M, int N, int K, int Kh) {
    __shared__ alignas(16) ushort As[128 * 64];
    __shared__ alignas(16) ushort Bs[64 * 64];
    int t = threadIdx.x, lane = t & 63, w = t >> 6;
    int bm = blockIdx.x * 128, bn = blockIdx.y * 64;
    int kbeg = blockIdx.z * Kh;
    int wm = (w >> 1) * 64, wn = (w & 1) * 32;
    f32x4 acc[4][2] = {};
    int srow = lane >> 3;
    int schunk = (lane & 7) ^ (lane >> 3);
    int rs = lane & 15, qd = lane >> 4;

    for (int k0 = kbeg; k0 < kbeg + Kh; k0 += 64) {
        __syncthreads();
#pragma unroll
        for (int i = 0; i < 4; i++) {
            int rr = w * 32 + i * 8;
            gl_lds16(A + (size_t)(bm + rr + srow) * K + k0 + schunk * 8, &As[rr * 64]);
        }
#pragma unroll
        for (int i = 0; i < 2; i++) {
            int rr = w * 16 + i * 8;
            gl_lds16(Bt + (size_t)(bn + rr + srow) * K + k0 + schunk * 8, &Bs[rr * 64]);
        }
        __syncthreads();
#pragma unroll
        for (int half = 0; half < 2; half++) {
            int cq = qd + half * 4;
            short8 af[4], bfr[2];
#pragma unroll
            for (int i = 0; i < 4; i++) {
                int ml = wm + i * 16 + rs;
                af[i] = *(const short8*)&As[ml * 64 + ((cq ^ (ml & 7)) * 8)];
            }
#pragma unroll
            for (int j = 0; j < 2; j++) {
                int nl = wn + j * 16 + rs;
                bfr[j] = *(const short8*)&Bs[nl * 64 + ((cq ^ (nl & 7)) * 8)];
            }
#pragma unroll
            for (int mi = 0; mi < 4; mi++)
#pragma unroll
                for (int ni = 0; ni < 2; ni++)
                    acc[mi][ni] = MFMA(af[mi], bfr[ni], acc[mi][ni], 0, 0, 0);
        }
    }
#pragma unroll
    for (int mi = 0; mi < 4; mi++)
#pragma unroll
        for (int ni = 0; ni < 2; ni++) {
            int row = bm + wm + mi * 16 + qd * 4;
            int col = bn + wn + ni * 16 + rs;
#pragma unroll
            for (int r = 0; r < 4; r++) {
                float v = acc[mi][ni][r];
                size_t idx = (size_t)(row + r) * N + col;
                if (EPI == 4) {
                    atomicAdd((float*)&C[idx], v);
                } else {
                    if (EPI == 1) v += R[idx];
                    st_out(&C[idx], v);
                }
            }
        }
}

// -------- causal flash attention: triangle-paired, split-2, deterministic combine --------
__global__ __launch_bounds__(256) void attn_kernel(const ushort* __restrict__ qk,
                                                   const ushort* __restrict__ vT,
                                                   ushort* __restrict__ attnO,
                                                   float* __restrict__ pO,
                                                   float* __restrict__ pL) {
    __shared__ alignas(16) ushort Ks[128 * 64];   // wave w's P overlays [w*2048,+2048)
    __shared__ alignas(16) ushort VTs[64 * 128];
    int t = threadIdx.x, lane = t & 63, w = t >> 6;
    int p = blockIdx.x, bh = blockIdx.y, z = blockIdx.z;
    int bb = bh >> 4, h = bh & 15;
    const ushort* qkb = qk + (size_t)bb * 2048 * 2048;
    const ushort* qptr = qkb + h * 64;
    const ushort* kptr = qkb + 1024 + h * 64;
    const ushort* vtb  = vT + (size_t)bh * 64 * 2048;
    int rs = lane & 15, qd = lane >> 4;
    int krl = lane >> 3, kch = lane & 7;
    int vrl = lane >> 4, vch = lane & 15;
    int nkA = p / 2 + 1, nkB = (31 - p) / 2 + 1;
    int qts[2] = {p, 31 - p};
    int nks[2] = {nkA, nkB};
    int kb[2], ke[2];
    if (z == 0) { kb[0] = 0; ke[0] = nkA; kb[1] = 0;       ke[1] = 9 - nkA; }
    else        { kb[0] = 0; ke[0] = 0;   kb[1] = 9 - nkA; ke[1] = nkB;     }
    ushort* Pw = &Ks[w * 2048];

    for (int ph = 0; ph < 2; ph++) {
        if (kb[ph] >= ke[ph]) continue;
        int qt = qts[ph], nk = nks[ph];
        int q0 = qt * 64;
        int qrow = q0 + w * 16 + rs;
        short8 aq0 = *(const short8*)(qptr + (size_t)qrow * 2048 + qd * 8);
        short8 aq1 = *(const short8*)(qptr + (size_t)qrow * 2048 + 32 + qd * 8);
        int myq = q0 + w * 16 + qd * 4;
        f32x4 o_acc[4] = {};
        float l_part[4] = {0.f, 0.f, 0.f, 0.f};

        for (int kt = kb[ph]; kt < ke[ph]; kt++) {
            int k0 = kt * 128;
            __syncthreads();
#pragma unroll
            for (int i = 0; i < 4; i++) {
                int kk = w * 32 + i * 8 + krl;
                gl_lds16(kptr + (size_t)(k0 + kk) * 2048 + ((kch ^ (kk & 7)) * 8), &Ks[(w * 32 + i * 8) * 64]);
                int dd = w * 16 + i * 4 + vrl;
                gl_lds16(vtb + (size_t)dd * 2048 + k0 + ((vch ^ (dd & 15)) * 8), &VTs[(w * 16 + i * 4) * 128]);
            }
            __syncthreads();
            f32x4 s[8];
#pragma unroll
            for (int c = 0; c < 8; c++) {
                int kk = c * 16 + rs;
                short8 kf0 = *(const short8*)&Ks[kk * 64 + ((qd ^ (kk & 7)) * 8)];
                short8 kf1 = *(const short8*)&Ks[kk * 64 + (((qd + 4) ^ (kk & 7)) * 8)];
                f32x4 zz = {};
                zz = MFMA(aq0, kf0, zz, 0, 0, 0);
                zz = MFMA(aq1, kf1, zz, 0, 0, 0);
                s[c] = zz;
            }
            bool lastt = (kt == nk - 1);
#pragma unroll
            for (int c = 0; c < 8; c++) {
                int kk = k0 + c * 16 + rs;
#pragma unroll
                for (int r = 0; r < 4; r++) {
                    float pv = __expf(s[c][r]);
                    if (lastt && (kk > myq + r)) pv = 0.f;
                    s[c][r] = pv;
                    l_part[r] += pv;
                }
            }
            __syncthreads();
#pragma unroll
            for (int r = 0; r < 4; r++) {
                int row = qd * 4 + r;
#pragma unroll
                for (int c = 0; c < 8; c++) {
                    int chunk = c * 2 + (rs >> 3);
                    Pw[row * 128 + ((chunk ^ row) * 8) + (rs & 7)] = f2bf_hu(s[c][r]);
                }
            }
            short8 ap[4];
#pragma unroll
            for (int kc = 0; kc < 4; kc++)
                ap[kc] = *(const short8*)&Pw[rs * 128 + (((kc * 4 + qd) ^ rs) * 8)];
#pragma unroll
            for (int dt = 0; dt < 4; dt++) {
                int dd = dt * 16 + rs;
#pragma unroll
                for (int kc = 0; kc < 4; kc++) {
                    int g = kc * 4 + qd;
                    short8 bv = *(const short8*)&VTs[dd * 128 + ((g ^ (dd & 15)) * 8)];
                    o_acc[dt] = MFMA(ap[kc], bv, o_acc[dt], 0, 0, 0);
                }
            }
        }
#pragma unroll
        for (int r = 0; r < 4; r++)
#pragma unroll
            for (int off = 1; off < 16; off <<= 1)
                l_part[r] += __shfl_xor(l_part[r], off);
        if (ph == 0) {
#pragma unroll
            for (int dt = 0; dt < 4; dt++)
#pragma unroll
                for (int r = 0; r < 4; r++)
                    attnO[(size_t)(bb * 2048 + myq + r) * 1024 + h * 64 + dt * 16 + rs] =
                        f2bf(o_acc[dt][r] / l_part[r]);
        } else {
            int qb16 = 15 - p;
            size_t ob = ((size_t)(z * 32 + bh) * 16 + qb16) * 4096;
#pragma unroll
            for (int dt = 0; dt < 4; dt++)
#pragma unroll
                for (int r = 0; r < 4; r++)
                    pO[ob + (size_t)(w * 16 + qd * 4 + r) * 64 + dt * 16 + rs] = o_acc[dt][r];
            if (rs == 0)
#pragma unroll
                for (int r = 0; r < 4; r++)
                    pL[((size_t)(z * 32 + bh) * 16 + qb16) * 64 + w * 16 + qd * 4 + r] = l_part[r];
        }
    }
}

// -------- combine the two z-partials for q-tiles 16..31 --------
__global__ __launch_bounds__(256) void attn_comb_kernel(const float* __restrict__ pO,
                                                        const float* __restrict__ pL,
                                                        ushort* __restrict__ attnO) {
    int idx4 = (blockIdx.x * 256 + threadIdx.x) * 4;
    int dim = idx4 & 63, row = (idx4 >> 6) & 63, qb = (idx4 >> 12) & 15, bh = idx4 >> 16;
    float4 o0 = *(const float4*)(pO + idx4);
    float4 o1 = *(const float4*)(pO + 2097152 + idx4);
    float inv = 1.0f / (pL[idx4 >> 6] + pL[32768 + (idx4 >> 6)]);
    int grow = (bh >> 4) * 2048 + (16 + qb) * 64 + row;
    int col = (bh & 15) * 64 + dim;
    ushort r4[4] = { f2bf((o0.x + o1.x) * inv), f2bf((o0.y + o1.y) * inv),
                     f2bf((o0.z + o1.z) * inv), f2bf((o0.w + o1.w) * inv) };
    *(uint2*)(attnO + (size_t)grow * 1024 + col) = *(uint2*)r4;
}

extern "C" void kernel_launch(void* const* d_in, const int* in_sizes, int n_in,
                              void* d_out, int out_size, void* d_ws, size_t ws_size,
                              hipStream_t stream) {
    const float* x     = (const float*)d_in[0];
    const float* ln1g  = (const float*)d_in[1];
    const float* ln1b  = (const float*)d_in[2];
    const float* wqkv  = (const float*)d_in[3];
    const float* wproj = (const float*)d_in[4];
    const float* ln2g  = (const float*)d_in[5];
    const float* ln2b  = (const float*)d_in[6];
    const float* wfc1  = (const float*)d_in[7];
    const float* wfc2  = (const float*)d_in[8];
    float* out = (float*)d_out;
    char* ws = (char*)d_ws;
    const size_t MB = 1024 * 1024;

    ushort* wbufA = (ushort*)(ws);
    ushort* lnbuf = (ushort*)(ws + 8 * MB);
    ushort* qk    = (ushort*)(ws + 16 * MB);
    ushort* vT    = (ushort*)(ws + 32 * MB);
    float*  pL    = (float*)(ws + 40 * MB);
    const int Rr = 4096;

    ln_kernel<<<Rr, 256, 0, stream>>>(x, ln1g, ln1b, lnbuf);
    wt_kernel<<<dim3(3072 / 32, 1024 / 32), 256, 0, stream>>>(wqkv, wbufA, 1024, 3072);
    gemm_kernel<3><<<dim3(3072 / 128, Rr / 128), 256, 0, stream>>>(lnbuf, wbufA, qk, vT, Rr, 3072, 1024);
    attn_kernel<<<dim3(16, 32, 2), 256, 0, stream>>>(qk, vT, lnbuf, out, pL);
    attn_comb_kernel<<<2048, 256, 0, stream>>>(out, pL, lnbuf);
    wt_kernel<<<dim3(1024 / 32, 1024 / 32), 256, 0, stream>>>(wproj, wbufA, 1024, 1024);
    gemm_n64_kernel<1, float><<<dim3(Rr / 128, 1024 / 64, 1), 256, 0, stream>>>(lnbuf, wbufA, out, x, Rr, 1024, 1024, 1024);
    ln_kernel<<<Rr, 256, 0, stream>>>(out, ln2g, ln2b, lnbuf);
    wt_kernel<<<dim3(4096 / 32, 1024 / 32), 256, 0, stream>>>(wfc1, wbufA, 1024, 4096);

    if (ws_size >= 56 * MB) {
        ushort* hmid  = qk;                                  // [16,48M)
        ushort* wbufB = (ushort*)(ws + 48 * MB);
        wt_kernel<<<dim3(1024 / 32, 4096 / 32), 256, 0, stream>>>(wfc2, wbufB, 4096, 1024);
        gemm_kernel<2><<<dim3(4096 / 128, Rr / 128), 256, 0, stream>>>(lnbuf, wbufA, hmid, nullptr, Rr, 4096, 1024);
        gemm_n64_kernel<4, float><<<dim3(Rr / 128, 1024 / 64, 2), 256, 0, stream>>>(hmid, wbufB, out, nullptr, Rr, 1024, 4096, 2048);
    } else {
        ushort* hmid  = qk;                                  // [16,32M)
        ushort* wbufB = (ushort*)(ws + 32 * MB);             // vT dead in FFN phase
        wt_kernel<<<dim3(1024 / 32, 4096 / 32), 256, 0, stream>>>(wfc2, wbufB, 4096, 1024);
        for (int hf = 0; hf < 2; hf++) {
            const ushort* lnh = lnbuf + (size_t)hf * 2048 * 1024;
            float* outh = out + (size_t)hf * 2048 * 1024;
            gemm_kernel<2><<<dim3(4096 / 128, 2048 / 128), 256, 0, stream>>>(lnh, wbufA, hmid, nullptr, 2048, 4096, 1024);
            gemm_n64_kernel<4, float><<<dim3(2048 / 128, 1024 / 64, 2), 256, 0, stream>>>(hmid, wbufB, outh, nullptr, 2048, 1024, 4096, 2048);
        }
    }
}

// Round 10
// 359.468 us; speedup vs baseline: 1.1261x; 1.0006x over previous
//
#include <hip/hip_runtime.h>
#include <math.h>

using short8 = __attribute__((ext_vector_type(8))) short;
using f32x4  = __attribute__((ext_vector_type(4))) float;
typedef unsigned short ushort;

__device__ inline ushort f2bf(float f) {
    union { float f; unsigned int i; } v; v.f = f;
    unsigned int x = v.i;
    return (ushort)((x + 0x7FFFu + ((x >> 16) & 1u)) >> 16);
}
__device__ inline ushort f2bf_hu(float f) {  // round-half-up (cheap, ~unbiased for p>=0)
    union { float f; unsigned int i; } v; v.f = f;
    return (ushort)((v.i + 0x8000u) >> 16);
}
__device__ inline void st_out(float* p, float v) { *p = v; }
__device__ inline void st_out(ushort* p, float v) { *p = f2bf(v); }

__device__ inline void gl_lds16(const ushort* g, ushort* l) {
    __builtin_amdgcn_global_load_lds((const __attribute__((address_space(1))) unsigned int*)g,
                                     (__attribute__((address_space(3))) unsigned int*)l, 16, 0, 0);
}
#define MFMA __builtin_amdgcn_mfma_f32_16x16x32_bf16

// tanh-approx GELU: ~8 VALU ops, |err| ~1e-3 (bf16 output rounding dominates)
__device__ inline float gelu_fast(float x) {
    float t2 = x * x;
    float y  = x * fmaf(t2, 0.07135481f, 1.5957691f);
    float e  = __expf(y);
    return x * e * __builtin_amdgcn_rcpf(e + 1.0f);
}

// ---------------- LayerNorm: one block per row of 1024; fp32 in, bf16 out ----------------
__global__ __launch_bounds__(256) void ln_kernel(const float* __restrict__ x,
                                                 const float* __restrict__ g,
                                                 const float* __restrict__ b,
                                                 ushort* __restrict__ y) {
    int row = blockIdx.x;
    const float* xr = x + (size_t)row * 1024;
    int t = threadIdx.x;
    float v[4];
    float s = 0.f, s2 = 0.f;
#pragma unroll
    for (int i = 0; i < 4; i++) {
        v[i] = xr[t + i * 256];
        s += v[i]; s2 += v[i] * v[i];
    }
#pragma unroll
    for (int off = 1; off < 64; off <<= 1) {
        s += __shfl_xor(s, off); s2 += __shfl_xor(s2, off);
    }
    __shared__ float ps[8];
    int w = t >> 6;
    if ((t & 63) == 0) { ps[w] = s; ps[4 + w] = s2; }
    __syncthreads();
    s  = ps[0] + ps[1] + ps[2] + ps[3];
    s2 = ps[4] + ps[5] + ps[6] + ps[7];
    float mu   = s * (1.0f / 1024.0f);
    float var  = s2 * (1.0f / 1024.0f) - mu * mu;
    float rinv = rsqrtf(var + 1e-5f);
    ushort* yr = y + (size_t)row * 1024;
#pragma unroll
    for (int i = 0; i < 4; i++) {
        int c = t + i * 256;
        yr[c] = f2bf((v[i] - mu) * rinv * g[c] + b[c]);
    }
}

// ------------- weight transpose+convert: fp32 [K,N] -> bf16 [N,K] -------------
__global__ __launch_bounds__(256) void wt_kernel(const float* __restrict__ s,
                                                 ushort* __restrict__ d, int K, int N) {
    __shared__ float tile[32][33];
    int n0 = blockIdx.x * 32, k0 = blockIdx.y * 32;
    int tx = threadIdx.x & 31, ty = threadIdx.x >> 5;
#pragma unroll
    for (int i = 0; i < 4; i++)
        tile[ty + i * 8][tx] = s[(size_t)(k0 + ty + i * 8) * N + n0 + tx];
    __syncthreads();
#pragma unroll
    for (int i = 0; i < 4; i++)
        d[(size_t)(n0 + ty + i * 8) * K + k0 + tx] = f2bf(tile[tx][ty + i * 8]);
}

// -------- bf16 MFMA GEMM: C = A[M,K] @ Bt[N,K]^T, 128x128 tile, BK=64, bf16 out --------
// 512 threads: 8 waves of 32(M)x64(N) -> acc 2x4 (32 AGPR) for 3 blocks/CU occupancy.
// EPI: 0 plain, 2 fast GELU, 3 QKV-split (Q*0.125,K -> qk stride 2048; V -> VT[d][t]).
template <int EPI>
__global__ __launch_bounds__(512, 6) void gemm_kernel(const ushort* __restrict__ A,
                                                      const ushort* __restrict__ Bt,
                                                      ushort* __restrict__ C,
                                                      ushort* __restrict__ VT,
                                                      int M, int N, int K) {
    __shared__ alignas(16) ushort SMEM[128 * 128];
    ushort* As = SMEM;
    ushort* Bs = SMEM + 128 * 64;
    int t = threadIdx.x, lane = t & 63, w = t >> 6;        // w in 0..7
    int bm = blockIdx.y * 128, bn = blockIdx.x * 128;
    int wm = (w & 3) * 32, wn = (w >> 2) * 64;
    f32x4 acc[2][4] = {};
    int srow = lane >> 3;
    int schunk = (lane & 7) ^ (lane >> 3);
    int rs = lane & 15, qd = lane >> 4;

    for (int k0 = 0; k0 < K; k0 += 64) {
        __syncthreads();
#pragma unroll
        for (int i = 0; i < 2; i++) {
            int rr = w * 16 + i * 8;
            gl_lds16(A  + (size_t)(bm + rr + srow) * K + k0 + schunk * 8, &As[rr * 64]);
            gl_lds16(Bt + (size_t)(bn + rr + srow) * K + k0 + schunk * 8, &Bs[rr * 64]);
        }
        __syncthreads();
#pragma unroll
        for (int half = 0; half < 2; half++) {
            int cq = qd + half * 4;
            short8 af[2], bf[4];
#pragma unroll
            for (int i = 0; i < 2; i++) {
                int ml = wm + i * 16 + rs;
                af[i] = *(const short8*)&As[ml * 64 + ((cq ^ (ml & 7)) * 8)];
            }
#pragma unroll
            for (int j = 0; j < 4; j++) {
                int nl = wn + j * 16 + rs;
                bf[j] = *(const short8*)&Bs[nl * 64 + ((cq ^ (nl & 7)) * 8)];
            }
#pragma unroll
            for (int mi = 0; mi < 2; mi++)
#pragma unroll
                for (int ni = 0; ni < 4; ni++)
                    acc[mi][ni] = MFMA(af[mi], bf[ni], acc[mi][ni], 0, 0, 0);
        }
    }

    if (EPI == 3 && bn >= 2048) {
        // V region: direct transposed store (already vectorized)
#pragma unroll
        for (int mi = 0; mi < 2; mi++)
#pragma unroll
            for (int ni = 0; ni < 4; ni++) {
                int row = bm + wm + mi * 16 + qd * 4;
                int col = bn + wn + ni * 16 + rs;
                int rel = col - 2048, hh = rel >> 6, dd = rel & 63;
                ushort tmp[4];
#pragma unroll
                for (int r = 0; r < 4; r++) tmp[r] = f2bf(acc[mi][ni][r]);
                size_t base = ((size_t)((row >> 11) * 16 + hh) * 64 + dd) * 2048 + (row & 2047);
                *(uint2*)&VT[base] = *(uint2*)tmp;
            }
        return;
    }

    // ---- staged epilogue: SMEM swizzled, then 16B coalesced stores ----
    float sc = (EPI == 3 && bn < 1024) ? 0.125f : 1.0f;
    __syncthreads();
#pragma unroll
    for (int mi = 0; mi < 2; mi++)
#pragma unroll
        for (int ni = 0; ni < 4; ni++) {
            int lcolc = (wn + ni * 16 + rs) >> 3;
            int lcolo = rs & 7;
#pragma unroll
            for (int r = 0; r < 4; r++) {
                int row = wm + mi * 16 + qd * 4 + r;
                float v = acc[mi][ni][r];
                if (EPI == 2) v = gelu_fast(v);
                if (EPI == 3) v *= sc;
                SMEM[row * 128 + ((lcolc ^ (row & 15)) * 8) + lcolo] = f2bf(v);
            }
        }
    __syncthreads();
    int ldC = (EPI == 3) ? 2048 : N;
#pragma unroll
    for (int ps = 0; ps < 4; ps++) {
        int row = ps * 32 + (t >> 4);
        int c = t & 15;
        short8 vv = *(const short8*)&SMEM[row * 128 + ((c ^ (row & 15)) * 8)];
        *(short8*)(C + (size_t)(bm + row) * ldC + bn + c * 8) = vv;
    }
}

// -------- bf16 MFMA GEMM: 128(M) x 64(N) tile, BK=64, split-K via grid.z --------
// 512 threads: 8 waves of 32x32 (acc 2x2, 16 AGPR). EPI: 1 = +fp32 R store, 4 = atomicAdd.
template <int EPI, typename CT>
__global__ __launch_bounds__(512, 6) void gemm_n64_kernel(const ushort* __restrict__ A,
                                                          const ushort* __restrict__ Bt,
                                                          CT* __restrict__ C,
                                                          const float* __restrict__ R,
                                                          int M, int N, int K, int Kh) {
    __shared__ alignas(16) ushort As[128 * 64];
    __shared__ alignas(16) ushort Bs[64 * 64];
    int t = threadIdx.x, lane = t & 63, w = t >> 6;
    int bm = blockIdx.x * 128, bn = blockIdx.y * 64;
    int kbeg = blockIdx.z * Kh;
    int wm = (w & 3) * 32, wn = (w >> 2) * 32;
    f32x4 acc[2][2] = {};
    int srow = lane >> 3;
    int schunk = (lane & 7) ^ (lane >> 3);
    int rs = lane & 15, qd = lane >> 4;

    for (int k0 = kbeg; k0 < kbeg + Kh; k0 += 64) {
        __syncthreads();
#pragma unroll
        for (int i = 0; i < 2; i++) {
            int rr = w * 16 + i * 8;
            gl_lds16(A + (size_t)(bm + rr + srow) * K + k0 + schunk * 8, &As[rr * 64]);
        }
        {
            int rr = w * 8;
            gl_lds16(Bt + (size_t)(bn + rr + srow) * K + k0 + schunk * 8, &Bs[rr * 64]);
        }
        __syncthreads();
#pragma unroll
        for (int half = 0; half < 2; half++) {
            int cq = qd + half * 4;
            short8 af[2], bfr[2];
#pragma unroll
            for (int i = 0; i < 2; i++) {
                int ml = wm + i * 16 + rs;
                af[i] = *(const short8*)&As[ml * 64 + ((cq ^ (ml & 7)) * 8)];
            }
#pragma unroll
            for (int j = 0; j < 2; j++) {
                int nl = wn + j * 16 + rs;
                bfr[j] = *(const short8*)&Bs[nl * 64 + ((cq ^ (nl & 7)) * 8)];
            }
#pragma unroll
            for (int mi = 0; mi < 2; mi++)
#pragma unroll
                for (int ni = 0; ni < 2; ni++)
                    acc[mi][ni] = MFMA(af[mi], bfr[ni], acc[mi][ni], 0, 0, 0);
        }
    }
#pragma unroll
    for (int mi = 0; mi < 2; mi++)
#pragma unroll
        for (int ni = 0; ni < 2; ni++) {
            int row = bm + wm + mi * 16 + qd * 4;
            int col = bn + wn + ni * 16 + rs;
#pragma unroll
            for (int r = 0; r < 4; r++) {
                float v = acc[mi][ni][r];
                size_t idx = (size_t)(row + r) * N + col;
                if (EPI == 4) {
                    atomicAdd((float*)&C[idx], v);
                } else {
                    if (EPI == 1) v += R[idx];
                    st_out(&C[idx], v);
                }
            }
        }
}

// -------- causal flash attention: triangle-paired, split-2, deterministic combine --------
__global__ __launch_bounds__(256) void attn_kernel(const ushort* __restrict__ qk,
                                                   const ushort* __restrict__ vT,
                                                   ushort* __restrict__ attnO,
                                                   float* __restrict__ pO,
                                                   float* __restrict__ pL) {
    __shared__ alignas(16) ushort Ks[128 * 64];   // wave w's P overlays [w*2048,+2048)
    __shared__ alignas(16) ushort VTs[64 * 128];
    int t = threadIdx.x, lane = t & 63, w = t >> 6;
    int p = blockIdx.x, bh = blockIdx.y, z = blockIdx.z;
    int bb = bh >> 4, h = bh & 15;
    const ushort* qkb = qk + (size_t)bb * 2048 * 2048;
    const ushort* qptr = qkb + h * 64;
    const ushort* kptr = qkb + 1024 + h * 64;
    const ushort* vtb  = vT + (size_t)bh * 64 * 2048;
    int rs = lane & 15, qd = lane >> 4;
    int krl = lane >> 3, kch = lane & 7;
    int vrl = lane >> 4, vch = lane & 15;
    int nkA = p / 2 + 1, nkB = (31 - p) / 2 + 1;
    int qts[2] = {p, 31 - p};
    int nks[2] = {nkA, nkB};
    int kb[2], ke[2];
    if (z == 0) { kb[0] = 0; ke[0] = nkA; kb[1] = 0;       ke[1] = 9 - nkA; }
    else        { kb[0] = 0; ke[0] = 0;   kb[1] = 9 - nkA; ke[1] = nkB;     }
    ushort* Pw = &Ks[w * 2048];

    for (int ph = 0; ph < 2; ph++) {
        if (kb[ph] >= ke[ph]) continue;
        int qt = qts[ph], nk = nks[ph];
        int q0 = qt * 64;
        int qrow = q0 + w * 16 + rs;
        short8 aq0 = *(const short8*)(qptr + (size_t)qrow * 2048 + qd * 8);
        short8 aq1 = *(const short8*)(qptr + (size_t)qrow * 2048 + 32 + qd * 8);
        int myq = q0 + w * 16 + qd * 4;
        f32x4 o_acc[4] = {};
        float l_part[4] = {0.f, 0.f, 0.f, 0.f};

        for (int kt = kb[ph]; kt < ke[ph]; kt++) {
            int k0 = kt * 128;
            __syncthreads();
#pragma unroll
            for (int i = 0; i < 4; i++) {
                int kk = w * 32 + i * 8 + krl;
                gl_lds16(kptr + (size_t)(k0 + kk) * 2048 + ((kch ^ (kk & 7)) * 8), &Ks[(w * 32 + i * 8) * 64]);
                int dd = w * 16 + i * 4 + vrl;
                gl_lds16(vtb + (size_t)dd * 2048 + k0 + ((vch ^ (dd & 15)) * 8), &VTs[(w * 16 + i * 4) * 128]);
            }
            __syncthreads();
            f32x4 s[8];
#pragma unroll
            for (int c = 0; c < 8; c++) {
                int kk = c * 16 + rs;
                short8 kf0 = *(const short8*)&Ks[kk * 64 + ((qd ^ (kk & 7)) * 8)];
                short8 kf1 = *(const short8*)&Ks[kk * 64 + (((qd + 4) ^ (kk & 7)) * 8)];
                f32x4 zz = {};
                zz = MFMA(aq0, kf0, zz, 0, 0, 0);
                zz = MFMA(aq1, kf1, zz, 0, 0, 0);
                s[c] = zz;
            }
            bool lastt = (kt == nk - 1);
#pragma unroll
            for (int c = 0; c < 8; c++) {
                int kk = k0 + c * 16 + rs;
#pragma unroll
                for (int r = 0; r < 4; r++) {
                    float pv = __expf(s[c][r]);
                    if (lastt && (kk > myq + r)) pv = 0.f;
                    s[c][r] = pv;
                    l_part[r] += pv;
                }
            }
            __syncthreads();
#pragma unroll
            for (int r = 0; r < 4; r++) {
                int row = qd * 4 + r;
#pragma unroll
                for (int c = 0; c < 8; c++) {
                    int chunk = c * 2 + (rs >> 3);
                    Pw[row * 128 + ((chunk ^ row) * 8) + (rs & 7)] = f2bf_hu(s[c][r]);
                }
            }
            short8 ap[4];
#pragma unroll
            for (int kc = 0; kc < 4; kc++)
                ap[kc] = *(const short8*)&Pw[rs * 128 + (((kc * 4 + qd) ^ rs) * 8)];
#pragma unroll
            for (int dt = 0; dt < 4; dt++) {
                int dd = dt * 16 + rs;
#pragma unroll
                for (int kc = 0; kc < 4; kc++) {
                    int g = kc * 4 + qd;
                    short8 bv = *(const short8*)&VTs[dd * 128 + ((g ^ (dd & 15)) * 8)];
                    o_acc[dt] = MFMA(ap[kc], bv, o_acc[dt], 0, 0, 0);
                }
            }
        }
#pragma unroll
        for (int r = 0; r < 4; r++)
#pragma unroll
            for (int off = 1; off < 16; off <<= 1)
                l_part[r] += __shfl_xor(l_part[r], off);
        if (ph == 0) {
#pragma unroll
            for (int dt = 0; dt < 4; dt++)
#pragma unroll
                for (int r = 0; r < 4; r++)
                    attnO[(size_t)(bb * 2048 + myq + r) * 1024 + h * 64 + dt * 16 + rs] =
                        f2bf(o_acc[dt][r] / l_part[r]);
        } else {
            int qb16 = 15 - p;
            size_t ob = ((size_t)(z * 32 + bh) * 16 + qb16) * 4096;
#pragma unroll
            for (int dt = 0; dt < 4; dt++)
#pragma unroll
                for (int r = 0; r < 4; r++)
                    pO[ob + (size_t)(w * 16 + qd * 4 + r) * 64 + dt * 16 + rs] = o_acc[dt][r];
            if (rs == 0)
#pragma unroll
                for (int r = 0; r < 4; r++)
                    pL[((size_t)(z * 32 + bh) * 16 + qb16) * 64 + w * 16 + qd * 4 + r] = l_part[r];
        }
    }
}

// -------- combine the two z-partials for q-tiles 16..31 --------
__global__ __launch_bounds__(256) void attn_comb_kernel(const float* __restrict__ pO,
                                                        const float* __restrict__ pL,
                                                        ushort* __restrict__ attnO) {
    int idx4 = (blockIdx.x * 256 + threadIdx.x) * 4;
    int dim = idx4 & 63, row = (idx4 >> 6) & 63, qb = (idx4 >> 12) & 15, bh = idx4 >> 16;
    float4 o0 = *(const float4*)(pO + idx4);
    float4 o1 = *(const float4*)(pO + 2097152 + idx4);
    float inv = 1.0f / (pL[idx4 >> 6] + pL[32768 + (idx4 >> 6)]);
    int grow = (bh >> 4) * 2048 + (16 + qb) * 64 + row;
    int col = (bh & 15) * 64 + dim;
    ushort r4[4] = { f2bf((o0.x + o1.x) * inv), f2bf((o0.y + o1.y) * inv),
                     f2bf((o0.z + o1.z) * inv), f2bf((o0.w + o1.w) * inv) };
    *(uint2*)(attnO + (size_t)grow * 1024 + col) = *(uint2*)r4;
}

extern "C" void kernel_launch(void* const* d_in, const int* in_sizes, int n_in,
                              void* d_out, int out_size, void* d_ws, size_t ws_size,
                              hipStream_t stream) {
    const float* x     = (const float*)d_in[0];
    const float* ln1g  = (const float*)d_in[1];
    const float* ln1b  = (const float*)d_in[2];
    const float* wqkv  = (const float*)d_in[3];
    const float* wproj = (const float*)d_in[4];
    const float* ln2g  = (const float*)d_in[5];
    const float* ln2b  = (const float*)d_in[6];
    const float* wfc1  = (const float*)d_in[7];
    const float* wfc2  = (const float*)d_in[8];
    float* out = (float*)d_out;
    char* ws = (char*)d_ws;
    const size_t MB = 1024 * 1024;

    ushort* wbufA = (ushort*)(ws);
    ushort* lnbuf = (ushort*)(ws + 8 * MB);
    ushort* qk    = (ushort*)(ws + 16 * MB);
    ushort* vT    = (ushort*)(ws + 32 * MB);
    float*  pL    = (float*)(ws + 40 * MB);
    const int Rr = 4096;

    ln_kernel<<<Rr, 256, 0, stream>>>(x, ln1g, ln1b, lnbuf);
    wt_kernel<<<dim3(3072 / 32, 1024 / 32), 256, 0, stream>>>(wqkv, wbufA, 1024, 3072);
    gemm_kernel<3><<<dim3(3072 / 128, Rr / 128), 512, 0, stream>>>(lnbuf, wbufA, qk, vT, Rr, 3072, 1024);
    attn_kernel<<<dim3(16, 32, 2), 256, 0, stream>>>(qk, vT, lnbuf, out, pL);
    attn_comb_kernel<<<2048, 256, 0, stream>>>(out, pL, lnbuf);
    // seed residual stream: out = x, then proj accumulates atomically (split-K=2)
    hipMemcpyAsync(out, x, (size_t)Rr * 1024 * 4, hipMemcpyDeviceToDevice, stream);
    wt_kernel<<<dim3(1024 / 32, 1024 / 32), 256, 0, stream>>>(wproj, wbufA, 1024, 1024);
    gemm_n64_kernel<4, float><<<dim3(Rr / 128, 1024 / 64, 2), 512, 0, stream>>>(lnbuf, wbufA, out, nullptr, Rr, 1024, 1024, 512);
    ln_kernel<<<Rr, 256, 0, stream>>>(out, ln2g, ln2b, lnbuf);
    wt_kernel<<<dim3(4096 / 32, 1024 / 32), 256, 0, stream>>>(wfc1, wbufA, 1024, 4096);

    if (ws_size >= 56 * MB) {
        ushort* hmid  = qk;                                  // [16,48M)
        ushort* wbufB = (ushort*)(ws + 48 * MB);
        wt_kernel<<<dim3(1024 / 32, 4096 / 32), 256, 0, stream>>>(wfc2, wbufB, 4096, 1024);
        gemm_kernel<2><<<dim3(4096 / 128, Rr / 128), 512, 0, stream>>>(lnbuf, wbufA, hmid, nullptr, Rr, 4096, 1024);
        gemm_n64_kernel<4, float><<<dim3(Rr / 128, 1024 / 64, 2), 512, 0, stream>>>(hmid, wbufB, out, nullptr, Rr, 1024, 4096, 2048);
    } else {
        ushort* hmid  = qk;                                  // [16,32M)
        ushort* wbufB = (ushort*)(ws + 32 * MB);             // vT dead in FFN phase
        wt_kernel<<<dim3(1024 / 32, 4096 / 32), 256, 0, stream>>>(wfc2, wbufB, 4096, 1024);
        for (int hf = 0; hf < 2; hf++) {
            const ushort* lnh = lnbuf + (size_t)hf * 2048 * 1024;
            float* outh = out + (size_t)hf * 2048 * 1024;
            gemm_kernel<2><<<dim3(4096 / 128, 2048 / 128), 512, 0, stream>>>(lnh, wbufA, hmid, nullptr, 2048, 4096, 1024);
            gemm_n64_kernel<4, float><<<dim3(2048 / 128, 1024 / 64, 2), 512, 0, stream>>>(hmid, wbufB, outh, nullptr, 2048, 1024, 4096, 2048);
        }
    }
}